// Round 16
// baseline (50.705 us; speedup 1.0000x reference)
//
#include <hip/hip_runtime.h>

#define NFEAT 40
#define EMB   64
#define ATT   32

// d_ws (u32 units): [0,1056) w-slices [a][kk][hk] 16B each (a=32 is p),
// [1088,1152) float2 {b_a, h_a*log2e} x 32
#define WS_WSL 0
#define WS_BH  1088

typedef __attribute__((ext_vector_type(8))) _Float16 f16x8;
typedef __attribute__((ext_vector_type(4))) float    f32x4;

template <int CTRL>
__device__ __forceinline__ float dpp_add_f(float v) {
  int t = __builtin_amdgcn_update_dpp(0, __float_as_int(v), CTRL, 0xF, 0xF, true);
  return v + __int_as_float(t);
}
__device__ __forceinline__ float rowsum16(float v) {
  v = dpp_add_f<0x128>(v);
  v = dpp_add_f<0x124>(v);
  v = dpp_add_f<0x122>(v);
  v = dpp_add_f<0x121>(v);
  return v;
}
__device__ __forceinline__ float xgroup_sum(float v) {
#if __has_builtin(__builtin_amdgcn_permlane16_swap) && __has_builtin(__builtin_amdgcn_permlane32_swap)
  {
    auto a = __builtin_amdgcn_permlane16_swap(__float_as_uint(v), __float_as_uint(v), false, false);
    v = __uint_as_float(a[0]) + __uint_as_float(a[1]);
    auto b = __builtin_amdgcn_permlane32_swap(__float_as_uint(v), __float_as_uint(v), false, false);
    v = __uint_as_float(b[0]) + __uint_as_float(b[1]);
  }
#else
  v += __shfl_xor(v, 16, 64);
  v += __shfl_xor(v, 32, 64);
#endif
  return v;
}

// ---------------- precompute: w-slices + bias/h into d_ws ----------------
extern "C" __global__ __launch_bounds__(256)
void afm_pre(const float* __restrict__ Wg, const float* __restrict__ bg,
             const float* __restrict__ hg, const float* __restrict__ pg,
             unsigned* __restrict__ ws) {
  const int tid = threadIdx.x;
  for (int o = tid; o < 33 * 2 * 4 * 4; o += 256) {
    int t2 = o & 3, hk = (o >> 2) & 3, kk = (o >> 4) & 1, a = o >> 5;
    unsigned out = 0;
#pragma unroll
    for (int s = 0; s < 2; s++) {
      int k = kk * 32 + hk * 8 + t2 * 2 + s;
      float v = (a < 32) ? Wg[k * ATT + a] : pg[k];
      _Float16 hv = (_Float16)v;
      out |= (unsigned)__builtin_bit_cast(unsigned short, hv) << (16 * s);
    }
    ws[WS_WSL + o] = out;
  }
  if (tid < 32) {
    float2 bh = {bg[tid], hg[tid] * 1.4426950408889634f};
    ((float2*)(ws + WS_BH))[tid] = bh;
  }
}

// ------ main: 1 wave = 1 batch, X in registers, Gram MFMAs, no LDS ------
extern "C" __global__ __launch_bounds__(256)
void afm_kernel(const float* __restrict__ xg, const unsigned* __restrict__ ws,
                float* __restrict__ outg, int nbatch) {
  const int lane = threadIdx.x & 63, wid = threadIdx.x >> 6;
  const int l15 = lane & 15, hk = lane >> 4;
  const int bb = blockIdx.x * 4 + wid;
  if (bb >= nbatch) return;

  // ---- stage X -> 6 register fragments (A/B dual-use layout) ----
  // frag(rb,kk): lane(l15,hk) holds x[rb*16+l15][kk*32+hk*8 .. +8] as f16
  const float* xb = xg + (size_t)bb * (NFEAT * EMB);
  f16x8 xf[3][2];
#pragma unroll
  for (int rb = 0; rb < 3; rb++) {
    int row = rb * 16 + l15;
    if (row > 39) row = 39;              // clamp; pad slots are masked below
    const float* rp = xb + row * EMB + hk * 8;
#pragma unroll
    for (int kk = 0; kk < 2; kk++) {
      float4 a = *(const float4*)(rp + kk * 32);
      float4 b = *(const float4*)(rp + kk * 32 + 4);
      xf[rb][kk] = f16x8{(_Float16)a.x, (_Float16)a.y, (_Float16)a.z, (_Float16)a.w,
                         (_Float16)b.x, (_Float16)b.y, (_Float16)b.z, (_Float16)b.w};
    }
  }

  const uint4*  wslp = (const uint4*)(ws + WS_WSL);
  const float2* bhp  = (const float2*)((const float*)ws + WS_BH);
  union { uint4 u; f16x8 h; } cv;

  // logit accumulators: 6 blocks (0,0)(0,1)(0,2)(1,1)(1,2)(2,2), 4 regs each
  f32x4 gl[6] = {};

  for (int a = 0; a < 32; a++) {
    cv.u = wslp[(a * 2 + 0) * 4 + hk]; const f16x8 w0 = cv.h;
    cv.u = wslp[(a * 2 + 1) * 4 + hk]; const f16x8 w1 = cv.h;
    const float2 bh = bhp[a];
    const f32x4 cb = {bh.x, bh.x, bh.x, bh.x};
    const f16x8 a00 = xf[0][0] * w0, a01 = xf[0][1] * w1;
    const f16x8 a10 = xf[1][0] * w0, a11 = xf[1][1] * w1;
    const f16x8 a20 = xf[2][0] * w0, a21 = xf[2][1] * w1;
    f32x4 g0 = __builtin_amdgcn_mfma_f32_16x16x32_f16(a00, xf[0][0], cb, 0, 0, 0);
    f32x4 g1 = __builtin_amdgcn_mfma_f32_16x16x32_f16(a00, xf[1][0], cb, 0, 0, 0);
    f32x4 g2 = __builtin_amdgcn_mfma_f32_16x16x32_f16(a00, xf[2][0], cb, 0, 0, 0);
    f32x4 g3 = __builtin_amdgcn_mfma_f32_16x16x32_f16(a10, xf[1][0], cb, 0, 0, 0);
    f32x4 g4 = __builtin_amdgcn_mfma_f32_16x16x32_f16(a10, xf[2][0], cb, 0, 0, 0);
    f32x4 g5 = __builtin_amdgcn_mfma_f32_16x16x32_f16(a20, xf[2][0], cb, 0, 0, 0);
    g0 = __builtin_amdgcn_mfma_f32_16x16x32_f16(a01, xf[0][1], g0, 0, 0, 0);
    g1 = __builtin_amdgcn_mfma_f32_16x16x32_f16(a01, xf[1][1], g1, 0, 0, 0);
    g2 = __builtin_amdgcn_mfma_f32_16x16x32_f16(a01, xf[2][1], g2, 0, 0, 0);
    g3 = __builtin_amdgcn_mfma_f32_16x16x32_f16(a11, xf[1][1], g3, 0, 0, 0);
    g4 = __builtin_amdgcn_mfma_f32_16x16x32_f16(a11, xf[2][1], g4, 0, 0, 0);
    g5 = __builtin_amdgcn_mfma_f32_16x16x32_f16(a21, xf[2][1], g5, 0, 0, 0);
    const float hL = bh.y;
#pragma unroll
    for (int r = 0; r < 4; r++) {
      gl[0][r] = fmaf(fmaxf(g0[r], 0.f), hL, gl[0][r]);
      gl[1][r] = fmaf(fmaxf(g1[r], 0.f), hL, gl[1][r]);
      gl[2][r] = fmaf(fmaxf(g2[r], 0.f), hL, gl[2][r]);
      gl[3][r] = fmaf(fmaxf(g3[r], 0.f), hL, gl[3][r]);
      gl[4][r] = fmaf(fmaxf(g4[r], 0.f), hL, gl[4][r]);
      gl[5][r] = fmaf(fmaxf(g5[r], 0.f), hL, gl[5][r]);
    }
  }

  // ---- e = exp2(logit) with validity masks; overwrite gl with e ----
  // slot (blk,reg): i = bi*16 + hk*4 + r, j = bj*16 + l15
  const bool jv = (l15 < 8);           // j < 40 for bj==2
  const int rr = hk * 4;
  float sum_e = 0.f;
#pragma unroll
  for (int r = 0; r < 4; r++) {
    const bool dlt = (rr + r) < l15;   // i<j within a diagonal block
    float e0 = dlt ? exp2f(gl[0][r]) : 0.f;
    float e1 =       exp2f(gl[1][r]);
    float e2 = jv  ? exp2f(gl[2][r]) : 0.f;
    float e3 = dlt ? exp2f(gl[3][r]) : 0.f;
    float e4 = jv  ? exp2f(gl[4][r]) : 0.f;
    float e5 = (dlt && jv) ? exp2f(gl[5][r]) : 0.f;
    gl[0][r] = e0; gl[1][r] = e1; gl[2][r] = e2;
    gl[3][r] = e3; gl[4][r] = e4; gl[5][r] = e5;
    sum_e += ((e0 + e1) + (e2 + e3)) + (e4 + e5);
  }

  // ---- p-Gram pass: s_p per slot, accumulate sum_es = e*s ----
  cv.u = wslp[(32 * 2 + 0) * 4 + hk]; const f16x8 p0 = cv.h;
  cv.u = wslp[(32 * 2 + 1) * 4 + hk]; const f16x8 p1 = cv.h;
  const f32x4 kz = {0.f, 0.f, 0.f, 0.f};
  {
    const f16x8 a00 = xf[0][0] * p0, a01 = xf[0][1] * p1;
    const f16x8 a10 = xf[1][0] * p0, a11 = xf[1][1] * p1;
    const f16x8 a20 = xf[2][0] * p0, a21 = xf[2][1] * p1;
    f32x4 s0 = __builtin_amdgcn_mfma_f32_16x16x32_f16(a00, xf[0][0], kz, 0, 0, 0);
    f32x4 s1 = __builtin_amdgcn_mfma_f32_16x16x32_f16(a00, xf[1][0], kz, 0, 0, 0);
    f32x4 s2 = __builtin_amdgcn_mfma_f32_16x16x32_f16(a00, xf[2][0], kz, 0, 0, 0);
    f32x4 s3 = __builtin_amdgcn_mfma_f32_16x16x32_f16(a10, xf[1][0], kz, 0, 0, 0);
    f32x4 s4 = __builtin_amdgcn_mfma_f32_16x16x32_f16(a10, xf[2][0], kz, 0, 0, 0);
    f32x4 s5 = __builtin_amdgcn_mfma_f32_16x16x32_f16(a20, xf[2][0], kz, 0, 0, 0);
    s0 = __builtin_amdgcn_mfma_f32_16x16x32_f16(a01, xf[0][1], s0, 0, 0, 0);
    s1 = __builtin_amdgcn_mfma_f32_16x16x32_f16(a01, xf[1][1], s1, 0, 0, 0);
    s2 = __builtin_amdgcn_mfma_f32_16x16x32_f16(a01, xf[2][1], s2, 0, 0, 0);
    s3 = __builtin_amdgcn_mfma_f32_16x16x32_f16(a11, xf[1][1], s3, 0, 0, 0);
    s4 = __builtin_amdgcn_mfma_f32_16x16x32_f16(a11, xf[2][1], s4, 0, 0, 0);
    s5 = __builtin_amdgcn_mfma_f32_16x16x32_f16(a21, xf[2][1], s5, 0, 0, 0);
    float sum_es = 0.f;
#pragma unroll
    for (int r = 0; r < 4; r++) {
      sum_es = fmaf(gl[0][r], s0[r], sum_es);
      sum_es = fmaf(gl[1][r], s1[r], sum_es);
      sum_es = fmaf(gl[2][r], s2[r], sum_es);
      sum_es = fmaf(gl[3][r], s3[r], sum_es);
      sum_es = fmaf(gl[4][r], s4[r], sum_es);
      sum_es = fmaf(gl[5][r], s5[r], sum_es);
    }
    // full 64-lane reduction (each valid pair counted exactly once)
    sum_e  = xgroup_sum(rowsum16(sum_e));
    sum_es = xgroup_sum(rowsum16(sum_es));
    if (lane == 0) outg[bb] = sum_es / sum_e;
  }
}

extern "C" void kernel_launch(void* const* d_in, const int* in_sizes, int n_in,
                              void* d_out, int out_size, void* d_ws, size_t ws_size,
                              hipStream_t stream) {
  const float* xg = (const float*)d_in[0];
  const float* Wg = (const float*)d_in[1];
  const float* bg = (const float*)d_in[2];
  const float* hg = (const float*)d_in[3];
  const float* pg = (const float*)d_in[4];
  float* outg = (float*)d_out;
  unsigned* ws = (unsigned*)d_ws;
  const int Bn = in_sizes[0] / (NFEAT * EMB);
  afm_pre<<<dim3(1), dim3(256), 0, stream>>>(Wg, bg, hg, pg, ws);
  afm_kernel<<<dim3((Bn + 3) / 4), dim3(256), 0, stream>>>(xg, ws, outg, Bn);
}

// Round 17
// 41.610 us; speedup vs baseline: 1.2186x; 1.2186x over previous
//
#include <hip/hip_runtime.h>

#define NFEAT 40
#define EMB   64
#define ATT   32
#define NPAIR 780
#define NTILE 49
#define XH_S  72                 // fp16 x LDS stride (elems) -> 144 B rows
#define XREG  (NFEAT * XH_S)     // 2880 elems = 5760 B per batch region

// d_ws (u32): [0,800) packed pair table; [1024,2560) W-frags 24 u32/lane;
// [4096,5120) per-lane 16 u32 {cb0 f32x4, cb1 f32x4, h2 u32x4 (f16 pairs), pad}
#define WS_PRT   0
#define WS_WF    1024
#define WS_CONST 4096

typedef __attribute__((ext_vector_type(8))) _Float16 f16x8;
typedef __attribute__((ext_vector_type(4))) float    f32x4;
typedef __attribute__((ext_vector_type(2))) unsigned u32x2;
typedef __attribute__((ext_vector_type(2))) __fp16   h2_t;

template <int CTRL>
__device__ __forceinline__ float dpp_add_f(float v) {
  int t = __builtin_amdgcn_update_dpp(0, __float_as_int(v), CTRL, 0xF, 0xF, true);
  return v + __int_as_float(t);
}
__device__ __forceinline__ float rowsum16(float v) {
  v = dpp_add_f<0x128>(v);
  v = dpp_add_f<0x124>(v);
  v = dpp_add_f<0x122>(v);
  v = dpp_add_f<0x121>(v);
  return v;
}
__device__ __forceinline__ float xgroup_sum(float v) {
#if __has_builtin(__builtin_amdgcn_permlane16_swap) && __has_builtin(__builtin_amdgcn_permlane32_swap)
  {
    auto a = __builtin_amdgcn_permlane16_swap(__float_as_uint(v), __float_as_uint(v), false, false);
    v = __uint_as_float(a[0]) + __uint_as_float(a[1]);
    auto b = __builtin_amdgcn_permlane32_swap(__float_as_uint(v), __float_as_uint(v), false, false);
    v = __uint_as_float(b[0]) + __uint_as_float(b[1]);
  }
#else
  v += __shfl_xor(v, 16, 64);
  v += __shfl_xor(v, 32, 64);
#endif
  return v;
}
__device__ __forceinline__ int pair_off(int i) { return 39 * i - (i * (i - 1)) / 2; }

// relu(score pair) . h pair, accumulating into c (f32)
__device__ __forceinline__ float reludot2(float s0, float s1, h2_t h2, float c) {
  h2_t r = __builtin_amdgcn_cvt_pkrtz(s0, s1);
  r = __builtin_elementwise_max(r, h2_t{(__fp16)0.f, (__fp16)0.f});
#if __has_builtin(__builtin_amdgcn_fdot2)
  return __builtin_amdgcn_fdot2(r, h2, c, false);
#else
  return fmaf((float)r[0], (float)h2[0], fmaf((float)r[1], (float)h2[1], c));
#endif
}

// ---------------- precompute kernel: fills d_ws once per launch ----------------
extern "C" __global__ __launch_bounds__(256)
void afm_pre(const float* __restrict__ Wg, const float* __restrict__ bg,
             const float* __restrict__ hg, const float* __restrict__ pg,
             unsigned* __restrict__ ws) {
  __shared__ float Wl[EMB * ATT];
  const int tid = threadIdx.x;
  const float L2E = 1.4426950408889634f;

  if (blockIdx.x == 0) {            // W fragments
    for (int f = tid; f < EMB * ATT / 4; f += 256)
      *(float4*)&Wl[f * 4] = ((const float4*)Wg)[f];
    __syncthreads();
    for (int o = tid; o < 1536; o += 256) {
      int lane = o / 24, rem = o % 24, frag = rem >> 2, pi = rem & 3;
      int kk = frag / 3, which = frag % 3;
      int l15 = lane & 15, hk = lane >> 4;
      unsigned out = 0;
#pragma unroll
      for (int s = 0; s < 2; s++) {
        int t = pi * 2 + s;
        int krow = kk * 32 + hk * 8 + t;
        float v = (which == 0) ? Wl[krow * ATT + l15]
                : (which == 1) ? Wl[krow * ATT + 16 + l15]
                               : ((l15 == 0) ? pg[krow] : 0.f);
        _Float16 hv = (_Float16)v;
        out |= (unsigned)__builtin_bit_cast(unsigned short, hv) << (16 * s);
      }
      ws[WS_WF + lane * 24 + rem] = out;
    }
  } else if (blockIdx.x == 1) {     // packed pair table
    for (int p = tid; p < NTILE * 16; p += 256) {
      int i = 0, j = 0;
      if (p < NPAIR) {
        i = (int)((79.0f - sqrtf(6241.0f - 8.0f * (float)p)) * 0.5f);
        if (i < 0) i = 0;
        while (pair_off(i + 1) <= p) ++i;
        while (pair_off(i) > p) --i;
        j = i + 1 + (p - pair_off(i));
      }
      int t = p >> 4, l = p & 15;
      ws[WS_PRT + (t >> 1) * 32 + l * 2 + (t & 1)] =
          (unsigned)(i * 144) | ((unsigned)(j * 144) << 16);
    }
  } else if (blockIdx.x == 2) {     // per-lane consts: cb0, cb1, h2(f16, *log2e)
    for (int o = tid; o < 1024; o += 256) {
      int lane = o >> 4, r = o & 15;
      int hk = lane >> 4;
      unsigned out;
      if (r < 4) out = __float_as_uint(bg[hk * 4 + r]);
      else if (r < 8) out = __float_as_uint(bg[16 + hk * 4 + (r - 4)]);
      else if (r < 12) {
        int q = r - 8;
        int a0 = (q < 2) ? (hk * 4 + 2 * q) : (16 + hk * 4 + 2 * (q - 2));
        __fp16 lo = (__fp16)(hg[a0] * L2E);
        __fp16 hi = (__fp16)(hg[a0 + 1] * L2E);
        out = (unsigned)__builtin_bit_cast(unsigned short, lo) |
              ((unsigned)__builtin_bit_cast(unsigned short, hi) << 16);
      } else out = 0;
      ws[WS_CONST + o] = out;
    }
  }
}

// ------- main: 4 waves/block, 1 batch/wave, grid ~1024, slim prologue -------
extern "C" __global__ __launch_bounds__(256)
void afm_kernel(const float* __restrict__ xg, const unsigned* __restrict__ ws,
                float* __restrict__ outg, int nbatch) {
  __shared__ __align__(16) _Float16 xh[4 * XREG];   // 23040 B

  const int lane = threadIdx.x & 63, wid = threadIdx.x >> 6;
  const int l15 = lane & 15, hk = lane >> 4;
  const int bb = blockIdx.x * 4 + wid;
  if (bb >= nbatch) return;

  // prologue: 6+3 coalesced dwordx4 loads
  union { uint4 u; f16x8 h; } cv;
  const uint4* wfp = (const uint4*)(ws + WS_WF + lane * 24);
  f16x8 wf0[2], wf1[2], wf2[2];
  cv.u = wfp[0]; wf0[0] = cv.h;
  cv.u = wfp[1]; wf1[0] = cv.h;
  cv.u = wfp[2]; wf2[0] = cv.h;
  cv.u = wfp[3]; wf0[1] = cv.h;
  cv.u = wfp[4]; wf1[1] = cv.h;
  cv.u = wfp[5]; wf2[1] = cv.h;
  const uint4* cp = (const uint4*)(ws + WS_CONST + lane * 16);
  const uint4 u0 = cp[0], u1 = cp[1], u2 = cp[2];
  const f32x4 cb0 = {__uint_as_float(u0.x), __uint_as_float(u0.y),
                     __uint_as_float(u0.z), __uint_as_float(u0.w)};
  const f32x4 cb1 = {__uint_as_float(u1.x), __uint_as_float(u1.y),
                     __uint_as_float(u1.z), __uint_as_float(u1.w)};
  union { unsigned u; h2_t h; } hcv;
  hcv.u = u2.x; const h2_t hp0 = hcv.h;
  hcv.u = u2.y; const h2_t hp1 = hcv.h;
  hcv.u = u2.z; const h2_t hp2 = hcv.h;
  hcv.u = u2.w; const h2_t hp3 = hcv.h;

  // stage x -> own LDS region: pkrtz, 8 elems/lane/iter
  _Float16* xw = &xh[wid * XREG];
  const float* xsrc = xg + (size_t)bb * (NFEAT * EMB);
#pragma unroll
  for (int it = 0; it < 5; it++) {
    int g0 = (it * 64 + lane) * 8;
    float4 a = *(const float4*)&xsrc[g0];
    float4 b = *(const float4*)&xsrc[g0 + 4];
    int row = g0 >> 6, c = g0 & 63;
    union { h2_t v2[4]; f16x8 v8; } pk;
    pk.v2[0] = __builtin_amdgcn_cvt_pkrtz(a.x, a.y);
    pk.v2[1] = __builtin_amdgcn_cvt_pkrtz(a.z, a.w);
    pk.v2[2] = __builtin_amdgcn_cvt_pkrtz(b.x, b.y);
    pk.v2[3] = __builtin_amdgcn_cvt_pkrtz(b.z, b.w);
    *(f16x8*)&xw[row * XH_S + c] = pk.v8;
  }
  __syncthreads();

  const unsigned wh = (unsigned)(wid * (XREG * 2) + hk * 16);
  const f32x4 kz = {0.f, 0.f, 0.f, 0.f};
  float sum_e = 0.f, sum_es = 0.f;

  auto tile = [&](unsigned pij) {
    const unsigned offi = (pij & 0xFFFFu) + wh;
    const unsigned offj = (pij >> 16) + wh;
    const f16x8 xi0 = *(const f16x8*)((const char*)xh + offi);
    const f16x8 xj0 = *(const f16x8*)((const char*)xh + offj);
    const f16x8 xi1 = *(const f16x8*)((const char*)xh + offi + 64);
    const f16x8 xj1 = *(const f16x8*)((const char*)xh + offj + 64);
    f16x8 af0 = xi0 * xj0;
    f16x8 af1 = xi1 * xj1;
    f32x4 a0 = __builtin_amdgcn_mfma_f32_16x16x32_f16(wf0[0], af0, cb0, 0, 0, 0);
    f32x4 a1 = __builtin_amdgcn_mfma_f32_16x16x32_f16(wf1[0], af0, cb1, 0, 0, 0);
    f32x4 a2 = __builtin_amdgcn_mfma_f32_16x16x32_f16(wf2[0], af0, kz, 0, 0, 0);
    a0 = __builtin_amdgcn_mfma_f32_16x16x32_f16(wf0[1], af1, a0, 0, 0, 0);
    a1 = __builtin_amdgcn_mfma_f32_16x16x32_f16(wf1[1], af1, a1, 0, 0, 0);
    a2 = __builtin_amdgcn_mfma_f32_16x16x32_f16(wf2[1], af1, a2, 0, 0, 0);
    float v = reludot2(a0[0], a0[1], hp0,
              reludot2(a0[2], a0[3], hp1,
              reludot2(a1[0], a1[1], hp2,
              reludot2(a1[2], a1[3], hp3, 0.f))));
    v = xgroup_sum(v);
    float e = exp2f(v);
    return make_float2(e, a2[0]);
  };

  u32x2 pp = *(const u32x2*)(ws + WS_PRT + l15 * 2);
#pragma unroll 8
  for (int k = 0; k < 24; ++k) {
    const unsigned pij0 = pp[0], pij1 = pp[1];
    if (k < 23) pp = *(const u32x2*)(ws + WS_PRT + (k + 1) * 32 + l15 * 2);
    float2 rA = tile(pij0);
    sum_e += rA.x;
    sum_es = fmaf(rA.x, rA.y, sum_es);
    float2 rB = tile(pij1);
    sum_e += rB.x;
    sum_es = fmaf(rB.x, rB.y, sum_es);
  }
  {  // peeled tail tile 48: pairs 780..783 are padding
    float2 rT = tile(ws[WS_PRT + 24 * 32 + l15 * 2]);
    float e = (l15 < 12) ? rT.x : 0.f;
    sum_e += e;
    sum_es = fmaf(e, rT.y, sum_es);
  }

  // row 0 holds each pair once (sum_es nonzero only on hk==0 lanes)
  sum_e  = rowsum16(sum_e);
  sum_es = rowsum16(sum_es);
  if (lane == 0) outg[bb] = sum_es / sum_e;
}

extern "C" void kernel_launch(void* const* d_in, const int* in_sizes, int n_in,
                              void* d_out, int out_size, void* d_ws, size_t ws_size,
                              hipStream_t stream) {
  const float* xg = (const float*)d_in[0];
  const float* Wg = (const float*)d_in[1];
  const float* bg = (const float*)d_in[2];
  const float* hg = (const float*)d_in[3];
  const float* pg = (const float*)d_in[4];
  float* outg = (float*)d_out;
  unsigned* ws = (unsigned*)d_ws;
  const int Bn = in_sizes[0] / (NFEAT * EMB);
  afm_pre<<<dim3(3), dim3(256), 0, stream>>>(Wg, bg, hg, pg, ws);
  afm_kernel<<<dim3((Bn + 3) / 4), dim3(256), 0, stream>>>(xg, ws, outg, Bn);
}

// Round 18
// 37.456 us; speedup vs baseline: 1.3537x; 1.1109x over previous
//
#include <hip/hip_runtime.h>

#define NFEAT 40
#define EMB   64
#define ATT   32
#define NPAIR 780
#define NTILE 49
#define XH_S  72                 // fp16 x LDS stride (elems) -> 144 B rows
#define XREG  (NFEAT * XH_S)     // 2880 elems = 5760 B per batch region

// d_ws (u32): [1024,2560) W-frags 24 u32/lane;
// [4096,5120) per-lane 16 u32 {cb0 f32x4, cb1 f32x4, h2 u32x4 (f16 pairs), pad}
#define WS_WF    1024
#define WS_CONST 4096

typedef __attribute__((ext_vector_type(8))) _Float16 f16x8;
typedef __attribute__((ext_vector_type(4))) float    f32x4;
typedef __attribute__((ext_vector_type(2))) unsigned u32x2;
typedef __attribute__((ext_vector_type(2))) __fp16   h2_t;

template <int CTRL>
__device__ __forceinline__ float dpp_add_f(float v) {
  int t = __builtin_amdgcn_update_dpp(0, __float_as_int(v), CTRL, 0xF, 0xF, true);
  return v + __int_as_float(t);
}
__device__ __forceinline__ float rowsum16(float v) {
  v = dpp_add_f<0x128>(v);
  v = dpp_add_f<0x124>(v);
  v = dpp_add_f<0x122>(v);
  v = dpp_add_f<0x121>(v);
  return v;
}
__device__ __forceinline__ float xgroup_sum(float v) {
#if __has_builtin(__builtin_amdgcn_permlane16_swap) && __has_builtin(__builtin_amdgcn_permlane32_swap)
  {
    auto a = __builtin_amdgcn_permlane16_swap(__float_as_uint(v), __float_as_uint(v), false, false);
    v = __uint_as_float(a[0]) + __uint_as_float(a[1]);
    auto b = __builtin_amdgcn_permlane32_swap(__float_as_uint(v), __float_as_uint(v), false, false);
    v = __uint_as_float(b[0]) + __uint_as_float(b[1]);
  }
#else
  v += __shfl_xor(v, 16, 64);
  v += __shfl_xor(v, 32, 64);
#endif
  return v;
}
__device__ __forceinline__ int pair_off(int i) { return 39 * i - (i * (i - 1)) / 2; }

// relu(score pair) . h pair, accumulating into c (f32)
__device__ __forceinline__ float reludot2(float s0, float s1, h2_t h2, float c) {
  h2_t r = __builtin_amdgcn_cvt_pkrtz(s0, s1);
  r = __builtin_elementwise_max(r, h2_t{(__fp16)0.f, (__fp16)0.f});
#if __has_builtin(__builtin_amdgcn_fdot2)
  return __builtin_amdgcn_fdot2(r, h2, c, false);
#else
  return fmaf((float)r[0], (float)h2[0], fmaf((float)r[1], (float)h2[1], c));
#endif
}

// ---------------- precompute kernel: fills d_ws once per launch ----------------
extern "C" __global__ __launch_bounds__(256)
void afm_pre(const float* __restrict__ Wg, const float* __restrict__ bg,
             const float* __restrict__ hg, const float* __restrict__ pg,
             unsigned* __restrict__ ws) {
  __shared__ float Wl[EMB * ATT];
  const int tid = threadIdx.x;
  const float L2E = 1.4426950408889634f;

  if (blockIdx.x == 0) {            // W fragments
    for (int f = tid; f < EMB * ATT / 4; f += 256)
      *(float4*)&Wl[f * 4] = ((const float4*)Wg)[f];
    __syncthreads();
    for (int o = tid; o < 1536; o += 256) {
      int lane = o / 24, rem = o % 24, frag = rem >> 2, pi = rem & 3;
      int kk = frag / 3, which = frag % 3;
      int l15 = lane & 15, hk = lane >> 4;
      unsigned out = 0;
#pragma unroll
      for (int s = 0; s < 2; s++) {
        int t = pi * 2 + s;
        int krow = kk * 32 + hk * 8 + t;
        float v = (which == 0) ? Wl[krow * ATT + l15]
                : (which == 1) ? Wl[krow * ATT + 16 + l15]
                               : ((l15 == 0) ? pg[krow] : 0.f);
        _Float16 hv = (_Float16)v;
        out |= (unsigned)__builtin_bit_cast(unsigned short, hv) << (16 * s);
      }
      ws[WS_WF + lane * 24 + rem] = out;
    }
  } else if (blockIdx.x == 1) {     // per-lane consts: cb0, cb1, h2(f16, *log2e)
    for (int o = tid; o < 1024; o += 256) {
      int lane = o >> 4, r = o & 15;
      int hk = lane >> 4;
      unsigned out;
      if (r < 4) out = __float_as_uint(bg[hk * 4 + r]);
      else if (r < 8) out = __float_as_uint(bg[16 + hk * 4 + (r - 4)]);
      else if (r < 12) {
        int q = r - 8;
        int a0 = (q < 2) ? (hk * 4 + 2 * q) : (16 + hk * 4 + 2 * (q - 2));
        __fp16 lo = (__fp16)(hg[a0] * L2E);
        __fp16 hi = (__fp16)(hg[a0 + 1] * L2E);
        out = (unsigned)__builtin_bit_cast(unsigned short, lo) |
              ((unsigned)__builtin_bit_cast(unsigned short, hi) << 16);
      } else out = 0;
      ws[WS_CONST + o] = out;
    }
  }
}

// ------- main: 8 waves/block, 1 batch/wave, grid = Bn/8 (2 blocks/CU) -------
extern "C" __global__ __launch_bounds__(512)
void afm_kernel(const float* __restrict__ xg, const unsigned* __restrict__ ws,
                float* __restrict__ outg, int nbatch) {
  __shared__ __align__(16) _Float16 xh[8 * XREG];   // 46080 B
  __shared__ unsigned prtp[25 * 32];                // 3200 B, [tilepair][l15][2]

  const int tid = threadIdx.x;
  const int lane = tid & 63, wid = tid >> 6;
  const int l15 = lane & 15, hk = lane >> 4;
  const int bb = blockIdx.x * 8 + wid;
  const bool live = bb < nbatch;

  // ---- pair table -> LDS (512 threads, 2 iters) ----
  for (int p = tid; p < NTILE * 16; p += 512) {
    int i = 0, j = 0;
    if (p < NPAIR) {
      i = (int)((79.0f - sqrtf(6241.0f - 8.0f * (float)p)) * 0.5f);
      if (i < 0) i = 0;
      while (pair_off(i + 1) <= p) ++i;
      while (pair_off(i) > p) --i;
      j = i + 1 + (p - pair_off(i));
    }
    int t = p >> 4, l = p & 15;
    prtp[(t >> 1) * 32 + l * 2 + (t & 1)] =
        (unsigned)(i * 144) | ((unsigned)(j * 144) << 16);
  }

  // ---- slim prologue: 6+3 coalesced dwordx4 loads from ws ----
  union { uint4 u; f16x8 h; } cv;
  const uint4* wfp = (const uint4*)(ws + WS_WF + lane * 24);
  f16x8 wf0[2], wf1[2], wf2[2];
  cv.u = wfp[0]; wf0[0] = cv.h;
  cv.u = wfp[1]; wf1[0] = cv.h;
  cv.u = wfp[2]; wf2[0] = cv.h;
  cv.u = wfp[3]; wf0[1] = cv.h;
  cv.u = wfp[4]; wf1[1] = cv.h;
  cv.u = wfp[5]; wf2[1] = cv.h;
  const uint4* cp = (const uint4*)(ws + WS_CONST + lane * 16);
  const uint4 u0 = cp[0], u1 = cp[1], u2 = cp[2];
  const f32x4 cb0 = {__uint_as_float(u0.x), __uint_as_float(u0.y),
                     __uint_as_float(u0.z), __uint_as_float(u0.w)};
  const f32x4 cb1 = {__uint_as_float(u1.x), __uint_as_float(u1.y),
                     __uint_as_float(u1.z), __uint_as_float(u1.w)};
  union { unsigned u; h2_t h; } hcv;
  hcv.u = u2.x; const h2_t hp0 = hcv.h;
  hcv.u = u2.y; const h2_t hp1 = hcv.h;
  hcv.u = u2.z; const h2_t hp2 = hcv.h;
  hcv.u = u2.w; const h2_t hp3 = hcv.h;

  // ---- stage x -> own LDS region: pkrtz, 8 elems/lane/iter ----
  _Float16* xw = &xh[wid * XREG];
  if (live) {
    const float* xsrc = xg + (size_t)bb * (NFEAT * EMB);
#pragma unroll
    for (int it = 0; it < 5; it++) {
      int g0 = (it * 64 + lane) * 8;
      float4 a = *(const float4*)&xsrc[g0];
      float4 b = *(const float4*)&xsrc[g0 + 4];
      int row = g0 >> 6, c = g0 & 63;
      union { h2_t v2[4]; f16x8 v8; } pk;
      pk.v2[0] = __builtin_amdgcn_cvt_pkrtz(a.x, a.y);
      pk.v2[1] = __builtin_amdgcn_cvt_pkrtz(a.z, a.w);
      pk.v2[2] = __builtin_amdgcn_cvt_pkrtz(b.x, b.y);
      pk.v2[3] = __builtin_amdgcn_cvt_pkrtz(b.z, b.w);
      *(f16x8*)&xw[row * XH_S + c] = pk.v8;
    }
  }
  __syncthreads();   // prt visible; own staging ordered; then free-run

  if (!live) return;
  const unsigned wh = (unsigned)(wid * (XREG * 2) + hk * 16);
  const f32x4 kz = {0.f, 0.f, 0.f, 0.f};
  float sum_e = 0.f, sum_es = 0.f;

  auto tile = [&](unsigned pij) {
    const unsigned offi = (pij & 0xFFFFu) + wh;
    const unsigned offj = (pij >> 16) + wh;
    const f16x8 xi0 = *(const f16x8*)((const char*)xh + offi);
    const f16x8 xj0 = *(const f16x8*)((const char*)xh + offj);
    const f16x8 xi1 = *(const f16x8*)((const char*)xh + offi + 64);
    const f16x8 xj1 = *(const f16x8*)((const char*)xh + offj + 64);
    f16x8 af0 = xi0 * xj0;
    f16x8 af1 = xi1 * xj1;
    f32x4 a0 = __builtin_amdgcn_mfma_f32_16x16x32_f16(wf0[0], af0, cb0, 0, 0, 0);
    f32x4 a1 = __builtin_amdgcn_mfma_f32_16x16x32_f16(wf1[0], af0, cb1, 0, 0, 0);
    f32x4 a2 = __builtin_amdgcn_mfma_f32_16x16x32_f16(wf2[0], af0, kz, 0, 0, 0);
    a0 = __builtin_amdgcn_mfma_f32_16x16x32_f16(wf0[1], af1, a0, 0, 0, 0);
    a1 = __builtin_amdgcn_mfma_f32_16x16x32_f16(wf1[1], af1, a1, 0, 0, 0);
    a2 = __builtin_amdgcn_mfma_f32_16x16x32_f16(wf2[1], af1, a2, 0, 0, 0);
    float v = reludot2(a0[0], a0[1], hp0,
              reludot2(a0[2], a0[3], hp1,
              reludot2(a1[0], a1[1], hp2,
              reludot2(a1[2], a1[3], hp3, 0.f))));
    v = xgroup_sum(v);
    float e = exp2f(v);
    return make_float2(e, a2[0]);
  };

  u32x2 pp = *(const u32x2*)&prtp[l15 * 2];
#pragma unroll 4
  for (int k = 0; k < 24; ++k) {
    const unsigned pij0 = pp[0], pij1 = pp[1];
    if (k < 23) pp = *(const u32x2*)&prtp[(k + 1) * 32 + l15 * 2];
    float2 rA = tile(pij0);
    sum_e += rA.x;
    sum_es = fmaf(rA.x, rA.y, sum_es);
    float2 rB = tile(pij1);
    sum_e += rB.x;
    sum_es = fmaf(rB.x, rB.y, sum_es);
  }
  {  // peeled tail tile 48: pairs 780..783 are padding
    float2 rT = tile(prtp[24 * 32 + l15 * 2]);
    float e = (l15 < 12) ? rT.x : 0.f;
    sum_e += e;
    sum_es = fmaf(e, rT.y, sum_es);
  }

  // row 0 holds each pair once (sum_es nonzero only on hk==0 lanes)
  sum_e  = rowsum16(sum_e);
  sum_es = rowsum16(sum_es);
  if (lane == 0) outg[bb] = sum_es / sum_e;
}

extern "C" void kernel_launch(void* const* d_in, const int* in_sizes, int n_in,
                              void* d_out, int out_size, void* d_ws, size_t ws_size,
                              hipStream_t stream) {
  const float* xg = (const float*)d_in[0];
  const float* Wg = (const float*)d_in[1];
  const float* bg = (const float*)d_in[2];
  const float* hg = (const float*)d_in[3];
  const float* pg = (const float*)d_in[4];
  float* outg = (float*)d_out;
  unsigned* ws = (unsigned*)d_ws;
  const int Bn = in_sizes[0] / (NFEAT * EMB);
  afm_pre<<<dim3(2), dim3(256), 0, stream>>>(Wg, bg, hg, pg, ws);
  afm_kernel<<<dim3((Bn + 7) / 8), dim3(512), 0, stream>>>(xg, ws, outg, Bn);
}

// Round 19
// 37.121 us; speedup vs baseline: 1.3659x; 1.0090x over previous
//
#include <hip/hip_runtime.h>

#define NFEAT 40
#define EMB   64
#define ATT   32
#define NPAIR 780
#define NTILE 49
#define XH_S  72                 // fp16 x LDS stride (elems) -> 144 B rows
#define XREG  (NFEAT * XH_S)     // 2880 elems = 5760 B per batch region

typedef __attribute__((ext_vector_type(8))) _Float16 f16x8;
typedef __attribute__((ext_vector_type(4))) float    f32x4;
typedef __attribute__((ext_vector_type(2))) unsigned u32x2;
typedef __attribute__((ext_vector_type(2))) __fp16   h2_t;

template <int CTRL>
__device__ __forceinline__ float dpp_add_f(float v) {
  int t = __builtin_amdgcn_update_dpp(0, __float_as_int(v), CTRL, 0xF, 0xF, true);
  return v + __int_as_float(t);
}
__device__ __forceinline__ float rowsum16(float v) {
  v = dpp_add_f<0x128>(v);
  v = dpp_add_f<0x124>(v);
  v = dpp_add_f<0x122>(v);
  v = dpp_add_f<0x121>(v);
  return v;
}
__device__ __forceinline__ float xgroup_sum(float v) {
#if __has_builtin(__builtin_amdgcn_permlane16_swap) && __has_builtin(__builtin_amdgcn_permlane32_swap)
  {
    auto a = __builtin_amdgcn_permlane16_swap(__float_as_uint(v), __float_as_uint(v), false, false);
    v = __uint_as_float(a[0]) + __uint_as_float(a[1]);
    auto b = __builtin_amdgcn_permlane32_swap(__float_as_uint(v), __float_as_uint(v), false, false);
    v = __uint_as_float(b[0]) + __uint_as_float(b[1]);
  }
#else
  v += __shfl_xor(v, 16, 64);
  v += __shfl_xor(v, 32, 64);
#endif
  return v;
}
__device__ __forceinline__ int pair_off(int i) { return 39 * i - (i * (i - 1)) / 2; }

// relu(score pair) . h pair (f16 dot into f32 acc)
__device__ __forceinline__ float reludot2(float s0, float s1, h2_t h2, float c) {
  h2_t r = __builtin_amdgcn_cvt_pkrtz(s0, s1);
  r = __builtin_elementwise_max(r, h2_t{(__fp16)0.f, (__fp16)0.f});
#if __has_builtin(__builtin_amdgcn_fdot2)
  return __builtin_amdgcn_fdot2(r, h2, c, false);
#else
  return fmaf((float)r[0], (float)h2[0], fmaf((float)r[1], (float)h2[1], c));
#endif
}

// ---- 4 waves/block, 2 batches PER WAVE (independent chains), grid Bn/8 ----
extern "C" __global__ __launch_bounds__(256)
void afm_kernel(const float* __restrict__ xg, const float* __restrict__ Wg,
                const float* __restrict__ bg, const float* __restrict__ hg,
                const float* __restrict__ pg, float* __restrict__ outg, int nbatch) {
  __shared__ __align__(16) _Float16 xh[8 * XREG];   // 46080 B (8 batch regions)
  __shared__ unsigned prtp[25 * 32];                // 3200 B [tilepair][l15][2]

  const int tid  = threadIdx.x;
  const int lane = tid & 63, wid = tid >> 6;
  const int l15  = lane & 15, hk = lane >> 4;
  const int bbA  = blockIdx.x * 8 + wid * 2;
  const int bbB  = bbA + 1;
  const bool liveA = bbA < nbatch, liveB = bbB < nbatch;

  // ---- pair table -> LDS, pair-packed ----
  for (int p = tid; p < NTILE * 16; p += 256) {
    int i = 0, j = 0;
    if (p < NPAIR) {
      i = (int)((79.0f - sqrtf(6241.0f - 8.0f * (float)p)) * 0.5f);
      if (i < 0) i = 0;
      while (pair_off(i + 1) <= p) ++i;
      while (pair_off(i) > p) --i;
      j = i + 1 + (p - pair_off(i));
    }
    int t = p >> 4, l = p & 15;
    prtp[(t >> 1) * 32 + l * 2 + (t & 1)] =
        (unsigned)(i * 144) | ((unsigned)(j * 144) << 16);
  }

  // ---- W fragments (A operand; D = [att][pair]); wf2 row0 = p ----
  f16x8 wf0[2], wf1[2], wf2[2];
#pragma unroll
  for (int kk = 0; kk < 2; kk++) {
    f16x8 r0, r1, r2;
#pragma unroll
    for (int t = 0; t < 8; t++) {
      int krow = kk * 32 + hk * 8 + t;
      r0[t] = (_Float16)Wg[krow * ATT + l15];
      r1[t] = (_Float16)Wg[krow * ATT + 16 + l15];
      _Float16 pv = (_Float16)pg[krow];
      r2[t] = (l15 == 0) ? pv : (_Float16)0.f;
    }
    wf0[kk] = r0; wf1[kk] = r1; wf2[kk] = r2;
  }
  const float4 b0 = *(const float4*)&bg[hk * 4];
  const float4 b1 = *(const float4*)&bg[16 + hk * 4];
  const f32x4 cb0 = {b0.x, b0.y, b0.z, b0.w};
  const f32x4 cb1 = {b1.x, b1.y, b1.z, b1.w};
  const float L2E = 1.4426950408889634f;
  const float4 hv0 = *(const float4*)&hg[hk * 4];
  const float4 hv1 = *(const float4*)&hg[16 + hk * 4];
  const h2_t hp0 = __builtin_amdgcn_cvt_pkrtz(hv0.x * L2E, hv0.y * L2E);
  const h2_t hp1 = __builtin_amdgcn_cvt_pkrtz(hv0.z * L2E, hv0.w * L2E);
  const h2_t hp2 = __builtin_amdgcn_cvt_pkrtz(hv1.x * L2E, hv1.y * L2E);
  const h2_t hp3 = __builtin_amdgcn_cvt_pkrtz(hv1.z * L2E, hv1.w * L2E);
  const f32x4 kz = {0.f, 0.f, 0.f, 0.f};

  // ---- stage both batches -> own LDS regions (pkrtz) ----
  auto stage = [&](int bb, int reg) {
    _Float16* xw = &xh[reg * XREG];
    const float* xsrc = xg + (size_t)bb * (NFEAT * EMB);
#pragma unroll
    for (int it = 0; it < 5; it++) {
      int g0 = (it * 64 + lane) * 8;
      float4 a = *(const float4*)&xsrc[g0];
      float4 b = *(const float4*)&xsrc[g0 + 4];
      int row = g0 >> 6, c = g0 & 63;
      union { h2_t v2[4]; f16x8 v8; } pk;
      pk.v2[0] = __builtin_amdgcn_cvt_pkrtz(a.x, a.y);
      pk.v2[1] = __builtin_amdgcn_cvt_pkrtz(a.z, a.w);
      pk.v2[2] = __builtin_amdgcn_cvt_pkrtz(b.x, b.y);
      pk.v2[3] = __builtin_amdgcn_cvt_pkrtz(b.z, b.w);
      *(f16x8*)&xh[reg * XREG + row * XH_S + c] = pk.v8;
    }
    (void)xw;
  };
  if (liveA) stage(bbA, wid * 2);
  if (liveB) stage(bbB, wid * 2 + 1);
  __syncthreads();   // prt + staging visible; waves free-run after

  const unsigned whA = (unsigned)(wid * 2 * (XREG * 2) + hk * 16);
  const unsigned whB = whA + (unsigned)(XREG * 2);
  float seA = 0.f, sesA = 0.f, seB = 0.f, sesB = 0.f;

  // one tile for one batch region; returns (e, s_p)
  auto tile = [&](unsigned pij, unsigned wh) {
    const unsigned offi = (pij & 0xFFFFu) + wh;
    const unsigned offj = (pij >> 16) + wh;
    const f16x8 xi0 = *(const f16x8*)((const char*)xh + offi);
    const f16x8 xj0 = *(const f16x8*)((const char*)xh + offj);
    const f16x8 xi1 = *(const f16x8*)((const char*)xh + offi + 64);
    const f16x8 xj1 = *(const f16x8*)((const char*)xh + offj + 64);
    f16x8 af0 = xi0 * xj0;
    f16x8 af1 = xi1 * xj1;
    f32x4 a0 = __builtin_amdgcn_mfma_f32_16x16x32_f16(wf0[0], af0, cb0, 0, 0, 0);
    f32x4 a1 = __builtin_amdgcn_mfma_f32_16x16x32_f16(wf1[0], af0, cb1, 0, 0, 0);
    f32x4 a2 = __builtin_amdgcn_mfma_f32_16x16x32_f16(wf2[0], af0, kz, 0, 0, 0);
    a0 = __builtin_amdgcn_mfma_f32_16x16x32_f16(wf0[1], af1, a0, 0, 0, 0);
    a1 = __builtin_amdgcn_mfma_f32_16x16x32_f16(wf1[1], af1, a1, 0, 0, 0);
    a2 = __builtin_amdgcn_mfma_f32_16x16x32_f16(wf2[1], af1, a2, 0, 0, 0);
    float v = reludot2(a0[0], a0[1], hp0,
              reludot2(a0[2], a0[3], hp1,
              reludot2(a1[0], a1[1], hp2,
              reludot2(a1[2], a1[3], hp3, 0.f))));
    v = xgroup_sum(v);
    float e = exp2f(v);
    return make_float2(e, a2[0]);
  };

  u32x2 pp = *(const u32x2*)&prtp[l15 * 2];
#pragma unroll 1
  for (int k = 0; k < 24; ++k) {
    const unsigned pij0 = pp[0], pij1 = pp[1];
    if (k < 23) pp = *(const u32x2*)&prtp[(k + 1) * 32 + l15 * 2];
    // A and B chains are fully independent -> co-scheduled by the compiler
    float2 rA0 = tile(pij0, whA);
    float2 rB0 = tile(pij0, whB);
    seA += rA0.x;  sesA = fmaf(rA0.x, rA0.y, sesA);
    seB += rB0.x;  sesB = fmaf(rB0.x, rB0.y, sesB);
    float2 rA1 = tile(pij1, whA);
    float2 rB1 = tile(pij1, whB);
    seA += rA1.x;  sesA = fmaf(rA1.x, rA1.y, sesA);
    seB += rB1.x;  sesB = fmaf(rB1.x, rB1.y, sesB);
  }
  {  // tail tile 48: pairs 780..783 are padding
    const unsigned pt = prtp[24 * 32 + l15 * 2];
    float2 rA = tile(pt, whA);
    float2 rB = tile(pt, whB);
    float eA = (l15 < 12) ? rA.x : 0.f;
    float eB = (l15 < 12) ? rB.x : 0.f;
    seA += eA;  sesA = fmaf(eA, rA.y, sesA);
    seB += eB;  sesB = fmaf(eB, rB.y, sesB);
  }

  // row 0 (hk==0) holds each pair once for ses; se identical across rows
  seA  = rowsum16(seA);
  sesA = rowsum16(sesA);
  seB  = rowsum16(seB);
  sesB = rowsum16(sesB);
  if (lane == 0) {
    if (liveA) outg[bbA] = sesA / seA;
    if (liveB) outg[bbB] = sesB / seB;
  }
}

extern "C" void kernel_launch(void* const* d_in, const int* in_sizes, int n_in,
                              void* d_out, int out_size, void* d_ws, size_t ws_size,
                              hipStream_t stream) {
  const float* xg = (const float*)d_in[0];
  const float* Wg = (const float*)d_in[1];
  const float* bg = (const float*)d_in[2];
  const float* hg = (const float*)d_in[3];
  const float* pg = (const float*)d_in[4];
  float* outg = (float*)d_out;
  const int Bn = in_sizes[0] / (NFEAT * EMB);
  afm_kernel<<<dim3((Bn + 7) / 8), dim3(256), 0, stream>>>(xg, Wg, bg, hg, pg, outg, Bn);
}